// Round 7
// baseline (7571.570 us; speedup 1.0000x reference)
//
#include <hip/hip_runtime.h>

// B=32, T=1024, I=H=512, 2H=1024.
// 64 WGs x 192 thr (3 waves): A=layer0 (binding cycle), B=layer1 (1-phase
// slack), C=all output stores. NO flags, NO drains: ring elements are
// tagged u64 {2xbf16, phase} stored via single dwordx2 sc1; consumers poll
// the data words directly (tag-in-data). LDS slot handoffs intra-WG.

#define T_STEPS 1024

typedef __bf16 bf8 __attribute__((ext_vector_type(8)));
typedef float  f4  __attribute__((ext_vector_type(4)));
typedef unsigned u32x4 __attribute__((ext_vector_type(4)));

__device__ __forceinline__ f4 mfma16(bf8 a, bf8 b, f4 c) {
    return __builtin_amdgcn_mfma_f32_16x16x32_bf16(a, b, c, 0, 0, 0);
}
__device__ __forceinline__ float sigf(float x)     { return 1.f / (1.f + __expf(-x)); }
__device__ __forceinline__ float tanhfast(float x) { return 1.f - 2.f / (1.f + __expf(2.f * x)); }
__device__ __forceinline__ unsigned pack2(float lo, float hi) {
    union { __bf16 h; unsigned short u; } a, b;
    a.h = (__bf16)lo; b.h = (__bf16)hi;
    return ((unsigned)b.u << 16) | (unsigned)a.u;
}
__device__ __forceinline__ void wait_lds_ge(int* p, int tgt) {
    while (__hip_atomic_load(p, __ATOMIC_ACQUIRE, __HIP_MEMORY_SCOPE_WORKGROUP) < tgt)
        __builtin_amdgcn_s_sleep(1);
}
__device__ __forceinline__ void set_lds(int* p, int v) {
    __hip_atomic_store(p, v, __ATOMIC_RELEASE, __HIP_MEMORY_SCOPE_WORKGROUP);
}

// ws: final_c f32 [32][2][512] at offset 0 (128KB).
// d_out (f32): seg0 out1, seg1 out2, seg2 con; seg2 scratch during run:
//   ti0 f32 [T*32][512] @ +0; xbf bf16 @ +16777216 f32; w0hi/w0lo next;
//   tagged rings @ +26214400 f32: ring0t u64[2][32][256], ring1t after
//   (256KB total; k_final overwrites later).

__global__ __launch_bounds__(256) void k_init(const float* __restrict__ x,
                                              const float* __restrict__ w_in0,
                                              __bf16* __restrict__ xbf,
                                              __bf16* __restrict__ w0hi,
                                              __bf16* __restrict__ w0lo,
                                              unsigned* __restrict__ ringz)
{
    size_t id = (size_t)blockIdx.x * 256 + threadIdx.x;
    size_t gs = (size_t)gridDim.x * 256;
    for (size_t i = id; i < 65536; i += gs) ringz[i] = 0u;   // both tagged rings
    for (size_t i = id; i < (size_t)16777216; i += gs) {
        size_t r = i >> 9, c = i & 511;
        size_t b = r & 31, t = r >> 5;
        xbf[i] = (__bf16)x[(((b << 10) + t) << 9) + c];
    }
    for (size_t i = id; i < (size_t)262144; i += gs) {
        size_t n = i >> 9, k = i & 511;
        float v = w_in0[(k << 9) + n];
        __bf16 h = (__bf16)v;
        w0hi[i] = h;
        w0lo[i] = (__bf16)(v - (float)h);
    }
}

__global__ __launch_bounds__(256) void k_pregemm(const __bf16* __restrict__ xbf,
                                                 const __bf16* __restrict__ w0hi,
                                                 const __bf16* __restrict__ w0lo,
                                                 const float* __restrict__ b_in0,
                                                 float* __restrict__ ti0)
{
    int tid = threadIdx.x, lane = tid & 63, wid = tid >> 6;
    int wg = blockIdx.x;
    int mbase = (wg & 511) * 64 + wid * 16;
    int nbase = (wg >> 9) * 128;
    int col = lane & 15, kgrp = lane >> 4;
    f4 acc[8];
#pragma unroll
    for (int i = 0; i < 8; ++i) acc[i] = (f4){0.f, 0.f, 0.f, 0.f};
    const __bf16* ap = xbf + (size_t)(mbase + col) * 512 + kgrp * 8;
    for (int kk = 0; kk < 16; ++kk) {
        bf8 a = *reinterpret_cast<const bf8*>(ap + kk * 32);
        const __bf16* wb = w0hi + (size_t)(nbase + col) * 512 + kk * 32 + kgrp * 8;
        const __bf16* wl = w0lo + (size_t)(nbase + col) * 512 + kk * 32 + kgrp * 8;
#pragma unroll
        for (int ct = 0; ct < 8; ++ct) {
            bf8 bh = *reinterpret_cast<const bf8*>(wb + (size_t)ct * 16 * 512);
            bf8 bl = *reinterpret_cast<const bf8*>(wl + (size_t)ct * 16 * 512);
            acc[ct] = mfma16(a, bh, acc[ct]);
            acc[ct] = mfma16(a, bl, acc[ct]);
        }
    }
#pragma unroll
    for (int ct = 0; ct < 8; ++ct) {
        int c = nbase + ct * 16 + col;
        float bias = b_in0[c];
#pragma unroll
        for (int r = 0; r < 4; ++r) {
            int row = mbase + kgrp * 4 + r;
            ti0[(size_t)row * 512 + c] = acc[ct][r] + bias;
        }
    }
}

// tagged ring pull: 32x dwordx4 sc1, retry until all 64 embedded tags == tg
__device__ __forceinline__ void pull_ring(const unsigned long long* rp, unsigned tg,
                                          bf8* afr)
{
    while (true) {
        u32x4 au[32];
#pragma unroll
        for (int kk = 0; kk < 16; ++kk) {
            asm volatile("global_load_dwordx4 %0, %1, off sc1"
                         : "=v"(au[2 * kk]) : "v"(rp + (size_t)kk * 16));
            asm volatile("global_load_dwordx4 %0, %1, off sc1"
                         : "=v"(au[2 * kk + 1]) : "v"(rp + (size_t)kk * 16 + 2));
        }
        asm volatile("s_waitcnt vmcnt(0)" ::: "memory");
        __builtin_amdgcn_sched_barrier(0);
        unsigned bad = 0;
#pragma unroll
        for (int i = 0; i < 32; ++i) bad |= (au[i][1] ^ tg) | (au[i][3] ^ tg);
        if (__ballot(bad == 0) == ~0ull) {
#pragma unroll
            for (int kk = 0; kk < 16; ++kk) {
                union { u32x4 u; bf8 v; } A;
                A.u = (u32x4){au[2 * kk][0], au[2 * kk][2],
                              au[2 * kk + 1][0], au[2 * kk + 1][2]};
                afr[kk] = A.v;
            }
            return;
        }
        __builtin_amdgcn_s_sleep(1);
    }
}

// ---------------- persistent recurrence
__global__ __launch_bounds__(192, 1) void k_recur(
    const float* __restrict__ wh0, const float* __restrict__ bh0g,
    const float* __restrict__ win1, const float* __restrict__ bin1g,
    const float* __restrict__ wh1, const float* __restrict__ bh1g,
    const float* __restrict__ ti0,
    float* __restrict__ out,
    float* __restrict__ fc,
    unsigned long long* __restrict__ ringbase)
{
    // planes: 0:w0r_hi 1:w0r_lo 2:w0m_hi 3:w0m_lo 4:w1r_hi 5:w1r_lo 6:w1m_hi 7:w1m_lo 8:wt_hi
    __shared__ __bf16 sW[9][8192];
    __shared__ float  sTi1[2][256];
    __shared__ float  sMn0[2][256];
    __shared__ float  sMn1[2][256];
    __shared__ float  sB[5][16];
    __shared__ int    sAready, sAout, sB1rdy, sBdone, sCdone;

    int tid = threadIdx.x, lane = tid & 63, wid = tid >> 6;   // 0=A,1=B,2=C
    int wg = blockIdx.x;
    int rank  = wg & 31;
    int mhalf = wg >> 5;

    unsigned long long* ring0t = ringbase;
    unsigned long long* ring1t = ringbase + 16384;

    int h0 = rank * 16;
    int col = lane & 15, kgrp = lane >> 4;
    int rbrow = mhalf * 16;

    for (int i = tid; i < 8192; i += 192) {
        int cl = i & 15, k = i >> 4;
        int sw = (cl * 512 + k) ^ ((cl & 7) << 3);
        float v0r = wh0[(size_t)k * 1024 + h0 + cl];
        float v0m = wh0[(size_t)k * 1024 + 512 + h0 + cl];
        float v1r = wh1[(size_t)k * 1024 + h0 + cl];
        float v1m = wh1[(size_t)k * 1024 + 512 + h0 + cl];
        float vt  = win1[(size_t)k * 512 + h0 + cl];
        __bf16 a;
        a = (__bf16)v0r; sW[0][sw] = a; sW[1][sw] = (__bf16)(v0r - (float)a);
        a = (__bf16)v0m; sW[2][sw] = a; sW[3][sw] = (__bf16)(v0m - (float)a);
        a = (__bf16)v1r; sW[4][sw] = a; sW[5][sw] = (__bf16)(v1r - (float)a);
        a = (__bf16)v1m; sW[6][sw] = a; sW[7][sw] = (__bf16)(v1m - (float)a);
        sW[8][sw] = (__bf16)vt;
    }
    if (tid < 16) {
        sB[0][tid] = bh0g[h0 + tid];
        sB[1][tid] = bh0g[512 + h0 + tid];
        sB[2][tid] = bh1g[h0 + tid];
        sB[3][tid] = bh1g[512 + h0 + tid];
        sB[4][tid] = bin1g[h0 + tid];
    }
    if (tid == 0) { sAready = -1; sAout = -1; sB1rdy = -1; sBdone = -1; sCdone = -1; }
    __syncthreads();

    float cs[4] = {0.f, 0.f, 0.f, 0.f};

    if (wid == 0) {
        // ============ wave A: layer-0 cycle + ti1 for B ============
#pragma unroll 1
        for (int ph = 0; ph <= T_STEPS; ++ph) {
            float t0v[4] = {0.f, 0.f, 0.f, 0.f};
            if (ph < T_STEPS) {
#pragma unroll
                for (int r = 0; r < 4; ++r)
                    t0v[r] = ti0[((size_t)ph * 32 + rbrow + kgrp * 4 + r) * 512 + h0 + col];
            }
            bf8 afr[16];
            pull_ring(ring0t + ((ph + 1) & 1) * 8192 + (size_t)(rbrow + col) * 256 + kgrp * 4,
                      (unsigned)ph, afr);
            f4 accR = {0.f, 0.f, 0.f, 0.f};
            f4 accM = {0.f, 0.f, 0.f, 0.f};
            f4 accT = {0.f, 0.f, 0.f, 0.f};
#pragma unroll
            for (int kk = 0; kk < 16; ++kk) {
                int e = (col * 512 + kk * 32 + kgrp * 8) ^ ((col & 7) << 3);
                accR = mfma16(afr[kk], *reinterpret_cast<const bf8*>(&sW[0][e]), accR);
                accR = mfma16(afr[kk], *reinterpret_cast<const bf8*>(&sW[1][e]), accR);
                accM = mfma16(afr[kk], *reinterpret_cast<const bf8*>(&sW[2][e]), accM);
                accM = mfma16(afr[kk], *reinterpret_cast<const bf8*>(&sW[3][e]), accM);
                accT = mfma16(afr[kk], *reinterpret_cast<const bf8*>(&sW[8][e]), accT);
            }
            wait_lds_ge(&sBdone, ph - 2);
#pragma unroll
            for (int r = 0; r < 4; ++r)
                sTi1[ph & 1][(kgrp * 4 + r) * 16 + col] = accT[r] + sB[4][col];
            if (lane == 0) set_lds(&sAready, ph);

            if (ph < T_STEPS) {
                float mn[4];
#pragma unroll
                for (int r = 0; r < 4; ++r) {
                    float retain = sigf(accR[r] + sB[0][col]);
                    float merge  = sigf(accM[r] + sB[1][col]);
                    float cv = tanhfast(cs[r] + retain * t0v[r]);
                    cs[r] = cv;
                    mn[r] = (1.f - merge) * t0v[r] + merge * cv;
                }
                unsigned tg1 = (unsigned)(ph + 1);
#pragma unroll
                for (int r = 0; r < 4; ++r) {
                    float hi = __shfl_xor(mn[r], 1, 64);
                    if (!(col & 1)) {
                        int grow = rbrow + kgrp * 4 + r;
                        unsigned long long w = ((unsigned long long)tg1 << 32) | pack2(mn[r], hi);
                        __hip_atomic_store(&ring0t[(ph & 1) * 8192 + (size_t)grow * 256 + rank * 8 + (col >> 1)],
                                           w, __ATOMIC_RELAXED, __HIP_MEMORY_SCOPE_AGENT);
                    }
                }
                // hand mn to C (C does all out-stores)
                wait_lds_ge(&sCdone, ph - 2);
#pragma unroll
                for (int r = 0; r < 4; ++r)
                    sMn0[ph & 1][(kgrp * 4 + r) * 16 + col] = mn[r];
                if (lane == 0) set_lds(&sAout, ph);
            }
        }
#pragma unroll
        for (int r = 0; r < 4; ++r) {
            int b = rbrow + kgrp * 4 + r;
            fc[((size_t)b * 2 + 0) * 512 + h0 + col] = cs[r];
        }
    } else if (wid == 1) {
        // ============ wave B: layer-1 (1-phase slack) ============
#pragma unroll 1
        for (int ph = 1; ph <= T_STEPS; ++ph) {
            bf8 afr[16];
            pull_ring(ring1t + (ph & 1) * 8192 + (size_t)(rbrow + col) * 256 + kgrp * 4,
                      (unsigned)(ph - 1), afr);
            f4 accR = {0.f, 0.f, 0.f, 0.f};
            f4 accM = {0.f, 0.f, 0.f, 0.f};
#pragma unroll
            for (int kk = 0; kk < 16; ++kk) {
                int e = (col * 512 + kk * 32 + kgrp * 8) ^ ((col & 7) << 3);
                accR = mfma16(afr[kk], *reinterpret_cast<const bf8*>(&sW[4][e]), accR);
                accR = mfma16(afr[kk], *reinterpret_cast<const bf8*>(&sW[5][e]), accR);
                accM = mfma16(afr[kk], *reinterpret_cast<const bf8*>(&sW[6][e]), accM);
                accM = mfma16(afr[kk], *reinterpret_cast<const bf8*>(&sW[7][e]), accM);
            }
            wait_lds_ge(&sAready, ph);
            float t1v[4];
#pragma unroll
            for (int r = 0; r < 4; ++r)
                t1v[r] = sTi1[ph & 1][(kgrp * 4 + r) * 16 + col];
            if (lane == 0) set_lds(&sBdone, ph);
            float mn[4];
#pragma unroll
            for (int r = 0; r < 4; ++r) {
                float retain = sigf(accR[r] + sB[2][col]);
                float merge  = sigf(accM[r] + sB[3][col]);
                float cv = tanhfast(cs[r] + retain * t1v[r]);
                cs[r] = cv;
                mn[r] = (1.f - merge) * t1v[r] + merge * cv;
            }
            unsigned tg1 = (unsigned)ph;
#pragma unroll
            for (int r = 0; r < 4; ++r) {
                float hi = __shfl_xor(mn[r], 1, 64);
                if (!(col & 1)) {
                    int grow = rbrow + kgrp * 4 + r;
                    unsigned long long w = ((unsigned long long)tg1 << 32) | pack2(mn[r], hi);
                    __hip_atomic_store(&ring1t[((ph + 1) & 1) * 8192 + (size_t)grow * 256 + rank * 8 + (col >> 1)],
                                       w, __ATOMIC_RELAXED, __HIP_MEMORY_SCOPE_AGENT);
                }
            }
            // hand mn to C
            wait_lds_ge(&sCdone, ph - 2);
#pragma unroll
            for (int r = 0; r < 4; ++r)
                sMn1[ph & 1][(kgrp * 4 + r) * 16 + col] = mn[r];
            if (lane == 0) set_lds(&sB1rdy, ph);
        }
#pragma unroll
        for (int r = 0; r < 4; ++r) {
            int b = rbrow + kgrp * 4 + r;
            fc[((size_t)b * 2 + 1) * 512 + h0 + col] = cs[r];
        }
    } else {
        // ============ wave C: all output stores ============
#pragma unroll 1
        for (int ph = 0; ph <= T_STEPS; ++ph) {
            float m0[4], m1[4];
            bool has0 = (ph < T_STEPS), has1 = (ph >= 1);
            if (has0) {
                wait_lds_ge(&sAout, ph);
#pragma unroll
                for (int r = 0; r < 4; ++r)
                    m0[r] = sMn0[ph & 1][(kgrp * 4 + r) * 16 + col];
            }
            if (has1) {
                wait_lds_ge(&sB1rdy, ph);
#pragma unroll
                for (int r = 0; r < 4; ++r)
                    m1[r] = sMn1[ph & 1][(kgrp * 4 + r) * 16 + col];
            }
            if (lane == 0) set_lds(&sCdone, ph);
            if (has0) {
#pragma unroll
                for (int r = 0; r < 4; ++r) {
                    int b = rbrow + kgrp * 4 + r;
                    size_t ob = ((size_t)b * 1024 + ph) * 1024 + h0 + col;
                    __builtin_nontemporal_store(m0[r], out + ob);
                    __builtin_nontemporal_store(m0[r], out + (size_t)33554432 + ob);
                }
            }
            if (has1) {
#pragma unroll
                for (int r = 0; r < 4; ++r) {
                    int b = rbrow + kgrp * 4 + r;
                    size_t ob = ((size_t)b * 1024 + (ph - 1)) * 1024 + 512 + h0 + col;
                    __builtin_nontemporal_store(m1[r], out + ob);
                    __builtin_nontemporal_store(m1[r], out + (size_t)33554432 + ob);
                }
            }
        }
    }
}

__global__ __launch_bounds__(256) void k_final(const float* __restrict__ fc,
                                               float* __restrict__ seg2)
{
    size_t id = (size_t)blockIdx.x * 256 + threadIdx.x;
    size_t gs = (size_t)gridDim.x * 256;
    for (size_t i = id; i < (size_t)8388608; i += gs) {
        size_t flat = i * 4;
        int h = (int)(flat & 511);
        int l = (int)((flat >> 9) & 1);
        int b = (int)(flat >> 20);
        f4 v = *reinterpret_cast<const f4*>(&fc[((size_t)b * 2 + l) * 512 + h]);
        *reinterpret_cast<f4*>(&seg2[flat]) = v;
    }
}

extern "C" void kernel_launch(void* const* d_in, const int* in_sizes, int n_in,
                              void* d_out, int out_size, void* d_ws, size_t ws_size,
                              hipStream_t stream)
{
    const float* x     = (const float*)d_in[0];
    const float* w_in0 = (const float*)d_in[1];
    const float* b_in0 = (const float*)d_in[2];
    const float* wh0   = (const float*)d_in[3];
    const float* bh0   = (const float*)d_in[4];
    const float* win1  = (const float*)d_in[5];
    const float* bin1  = (const float*)d_in[6];
    const float* wh1   = (const float*)d_in[7];
    const float* bh1   = (const float*)d_in[8];
    float* out = (float*)d_out;

    float*  seg2 = out + (size_t)2 * 33554432;
    float*  ti0  = seg2;
    __bf16* xbf  = (__bf16*)(ti0 + 16777216);
    __bf16* w0hi = xbf + 16777216;
    __bf16* w0lo = w0hi + 262144;
    unsigned long long* ringt = (unsigned long long*)(seg2 + 26214400);

    k_init<<<1024, 256, 0, stream>>>(x, w_in0, xbf, w0hi, w0lo, (unsigned*)ringt);
    k_pregemm<<<2048, 256, 0, stream>>>(xbf, w0hi, w0lo, b_in0, ti0);
    k_recur<<<64, 192, 0, stream>>>(wh0, bh0, win1, bin1, wh1, bh1, ti0, out,
                                    (float*)d_ws, ringt);
    k_final<<<1024, 256, 0, stream>>>((const float*)d_ws, seg2);
}

// Round 8
// 4479.070 us; speedup vs baseline: 1.6904x; 1.6904x over previous
//
#include <hip/hip_runtime.h>

// B=32, T=1024, I=H=512, 2H=1024.
// 64 WGs x 192 thr (3 waves): A=layer0 (binding cycle), B=layer1 (1-phase
// slack), C=all output stores. r6 flag protocol (validated) with:
// scattered per-rank flag lines, 32-lane polling, rank-major rings
// (exclusive cache lines per producer), vmcnt(8) load/MFMA overlap.

#define T_STEPS 1024

typedef __bf16 bf8 __attribute__((ext_vector_type(8)));
typedef float  f4  __attribute__((ext_vector_type(4)));
typedef unsigned u32x4 __attribute__((ext_vector_type(4)));

__device__ __forceinline__ f4 mfma16(bf8 a, bf8 b, f4 c) {
    return __builtin_amdgcn_mfma_f32_16x16x32_bf16(a, b, c, 0, 0, 0);
}
__device__ __forceinline__ float sigf(float x)     { return 1.f / (1.f + __expf(-x)); }
__device__ __forceinline__ float tanhfast(float x) { return 1.f - 2.f / (1.f + __expf(2.f * x)); }
__device__ __forceinline__ unsigned pack2(float lo, float hi) {
    union { __bf16 h; unsigned short u; } a, b;
    a.h = (__bf16)lo; b.h = (__bf16)hi;
    return ((unsigned)b.u << 16) | (unsigned)a.u;
}
__device__ __forceinline__ void wait_lds_ge(int* p, int tgt) {
    while (__hip_atomic_load(p, __ATOMIC_ACQUIRE, __HIP_MEMORY_SCOPE_WORKGROUP) < tgt)
        __builtin_amdgcn_s_sleep(1);
}
__device__ __forceinline__ void set_lds(int* p, int v) {
    __hip_atomic_store(p, v, __ATOMIC_RELEASE, __HIP_MEMORY_SCOPE_WORKGROUP);
}
// poll 32 scattered flags (64B stride): lanes<32 load, others vote true
__device__ __forceinline__ void poll_flags(const unsigned* fbase, unsigned tgt, int lane) {
    while (true) {
        unsigned v = 0xFFFFFFFFu;
        if (lane < 32)
            v = __hip_atomic_load(fbase + lane * 16, __ATOMIC_RELAXED,
                                  __HIP_MEMORY_SCOPE_AGENT);
        if (__ballot(v >= tgt) == ~0ull) break;
        __builtin_amdgcn_s_sleep(1);
    }
    __builtin_amdgcn_sched_barrier(0);
}

// ws layout (u32 units):
//   [0,1024)      : flagsA  (mhalf m at m*512 + rank*16)
//   [1024,2048)   : flagsB
//   [2048,18432)  : ring0  [slot2][rank32][row32][pair8] u32
//   [18432,34816) : ring1
//   [34816,67584) : final_c f32 [32][2][512]
// d_out (f32): seg0 out1, seg1 out2, seg2 con; seg2 scratch during run:
//   ti0 f32 [T*32][512] @ +0; xbf bf16 @ +16777216 f32; w0hi/w0lo next.

__global__ __launch_bounds__(256) void k_init(const float* __restrict__ x,
                                              const float* __restrict__ w_in0,
                                              __bf16* __restrict__ xbf,
                                              __bf16* __restrict__ w0hi,
                                              __bf16* __restrict__ w0lo,
                                              unsigned* __restrict__ ws)
{
    size_t id = (size_t)blockIdx.x * 256 + threadIdx.x;
    size_t gs = (size_t)gridDim.x * 256;
    for (size_t i = id; i < 34816; i += gs) ws[i] = 0u;   // flags + rings
    for (size_t i = id; i < (size_t)16777216; i += gs) {
        size_t r = i >> 9, c = i & 511;
        size_t b = r & 31, t = r >> 5;
        xbf[i] = (__bf16)x[(((b << 10) + t) << 9) + c];
    }
    for (size_t i = id; i < (size_t)262144; i += gs) {
        size_t n = i >> 9, k = i & 511;
        float v = w_in0[(k << 9) + n];
        __bf16 h = (__bf16)v;
        w0hi[i] = h;
        w0lo[i] = (__bf16)(v - (float)h);
    }
}

__global__ __launch_bounds__(256) void k_pregemm(const __bf16* __restrict__ xbf,
                                                 const __bf16* __restrict__ w0hi,
                                                 const __bf16* __restrict__ w0lo,
                                                 const float* __restrict__ b_in0,
                                                 float* __restrict__ ti0)
{
    int tid = threadIdx.x, lane = tid & 63, wid = tid >> 6;
    int wg = blockIdx.x;
    int mbase = (wg & 511) * 64 + wid * 16;
    int nbase = (wg >> 9) * 128;
    int col = lane & 15, kgrp = lane >> 4;
    f4 acc[8];
#pragma unroll
    for (int i = 0; i < 8; ++i) acc[i] = (f4){0.f, 0.f, 0.f, 0.f};
    const __bf16* ap = xbf + (size_t)(mbase + col) * 512 + kgrp * 8;
    for (int kk = 0; kk < 16; ++kk) {
        bf8 a = *reinterpret_cast<const bf8*>(ap + kk * 32);
        const __bf16* wb = w0hi + (size_t)(nbase + col) * 512 + kk * 32 + kgrp * 8;
        const __bf16* wl = w0lo + (size_t)(nbase + col) * 512 + kk * 32 + kgrp * 8;
#pragma unroll
        for (int ct = 0; ct < 8; ++ct) {
            bf8 bh = *reinterpret_cast<const bf8*>(wb + (size_t)ct * 16 * 512);
            bf8 bl = *reinterpret_cast<const bf8*>(wl + (size_t)ct * 16 * 512);
            acc[ct] = mfma16(a, bh, acc[ct]);
            acc[ct] = mfma16(a, bl, acc[ct]);
        }
    }
#pragma unroll
    for (int ct = 0; ct < 8; ++ct) {
        int c = nbase + ct * 16 + col;
        float bias = b_in0[c];
#pragma unroll
        for (int r = 0; r < 4; ++r) {
            int row = mbase + kgrp * 4 + r;
            ti0[(size_t)row * 512 + c] = acc[ct][r] + bias;
        }
    }
}

// ---------------- persistent recurrence
__global__ __launch_bounds__(192, 1) void k_recur(
    const float* __restrict__ wh0, const float* __restrict__ bh0g,
    const float* __restrict__ win1, const float* __restrict__ bin1g,
    const float* __restrict__ wh1, const float* __restrict__ bh1g,
    const float* __restrict__ ti0,
    float* __restrict__ out,
    unsigned* __restrict__ ws)
{
    // planes: 0:w0r_hi 1:w0r_lo 2:w0m_hi 3:w0m_lo 4:w1r_hi 5:w1r_lo 6:w1m_hi 7:w1m_lo 8:wt_hi
    __shared__ __bf16 sW[9][8192];
    __shared__ float  sTi1[2][256];
    __shared__ float  sMn0[2][256];
    __shared__ float  sMn1[2][256];
    __shared__ float  sB[5][16];
    __shared__ int    sAready, sAout, sB1rdy, sBdone, sCdone;

    int tid = threadIdx.x, lane = tid & 63, wid = tid >> 6;   // 0=A,1=B,2=C
    int wg = blockIdx.x;
    int rank  = wg & 31;
    int mhalf = wg >> 5;

    unsigned* flagsA = ws + mhalf * 512;
    unsigned* flagsB = ws + 1024 + mhalf * 512;
    unsigned* ring0d = ws + 2048;
    unsigned* ring1d = ws + 18432;
    float* fc = (float*)(ws + 34816);

    int h0 = rank * 16;
    int col = lane & 15, kgrp = lane >> 4;
    int rbrow = mhalf * 16;

    for (int i = tid; i < 8192; i += 192) {
        int cl = i & 15, k = i >> 4;
        int sw = (cl * 512 + k) ^ ((cl & 7) << 3);
        float v0r = wh0[(size_t)k * 1024 + h0 + cl];
        float v0m = wh0[(size_t)k * 1024 + 512 + h0 + cl];
        float v1r = wh1[(size_t)k * 1024 + h0 + cl];
        float v1m = wh1[(size_t)k * 1024 + 512 + h0 + cl];
        float vt  = win1[(size_t)k * 512 + h0 + cl];
        __bf16 a;
        a = (__bf16)v0r; sW[0][sw] = a; sW[1][sw] = (__bf16)(v0r - (float)a);
        a = (__bf16)v0m; sW[2][sw] = a; sW[3][sw] = (__bf16)(v0m - (float)a);
        a = (__bf16)v1r; sW[4][sw] = a; sW[5][sw] = (__bf16)(v1r - (float)a);
        a = (__bf16)v1m; sW[6][sw] = a; sW[7][sw] = (__bf16)(v1m - (float)a);
        sW[8][sw] = (__bf16)vt;
    }
    if (tid < 16) {
        sB[0][tid] = bh0g[h0 + tid];
        sB[1][tid] = bh0g[512 + h0 + tid];
        sB[2][tid] = bh1g[h0 + tid];
        sB[3][tid] = bh1g[512 + h0 + tid];
        sB[4][tid] = bin1g[h0 + tid];
    }
    if (tid == 0) { sAready = -1; sAout = -1; sB1rdy = -1; sBdone = -1; sCdone = -1; }
    __syncthreads();

    float cs[4] = {0.f, 0.f, 0.f, 0.f};

    if (wid == 0) {
        // ============ wave A: layer-0 cycle + ti1 for B ============
#pragma unroll 1
        for (int ph = 0; ph <= T_STEPS; ++ph) {
            float t0v[4] = {0.f, 0.f, 0.f, 0.f};
            if (ph < T_STEPS) {
#pragma unroll
                for (int r = 0; r < 4; ++r)
                    t0v[r] = ti0[((size_t)ph * 32 + rbrow + kgrp * 4 + r) * 512 + h0 + col];
            }
            if (ph > 0) poll_flags(flagsA, (unsigned)ph, lane);
            // rank-major ring pull: afr[kk] from rank (2kk + kgrp/2)
            u32x4 au[16];
            {
                const unsigned* rp = ring0d + ((ph + 1) & 1) * 8192
                                   + (rbrow + col) * 8 + (kgrp & 1) * 4;
#pragma unroll
                for (int kk = 0; kk < 16; ++kk)
                    asm volatile("global_load_dwordx4 %0, %1, off sc1"
                                 : "=v"(au[kk]) : "v"(rp + (2 * kk + (kgrp >> 1)) * 256));
            }
            f4 accR = {0.f, 0.f, 0.f, 0.f};
            f4 accM = {0.f, 0.f, 0.f, 0.f};
            f4 accT = {0.f, 0.f, 0.f, 0.f};
            asm volatile("s_waitcnt vmcnt(8)" ::: "memory");
            __builtin_amdgcn_sched_barrier(0);
#pragma unroll
            for (int kk = 0; kk < 8; ++kk) {
                union { u32x4 u; bf8 v; } A; A.u = au[kk];
                int e = (col * 512 + kk * 32 + kgrp * 8) ^ ((col & 7) << 3);
                accR = mfma16(A.v, *reinterpret_cast<const bf8*>(&sW[0][e]), accR);
                accR = mfma16(A.v, *reinterpret_cast<const bf8*>(&sW[1][e]), accR);
                accM = mfma16(A.v, *reinterpret_cast<const bf8*>(&sW[2][e]), accM);
                accM = mfma16(A.v, *reinterpret_cast<const bf8*>(&sW[3][e]), accM);
                accT = mfma16(A.v, *reinterpret_cast<const bf8*>(&sW[8][e]), accT);
            }
            asm volatile("s_waitcnt vmcnt(0)" ::: "memory");
            __builtin_amdgcn_sched_barrier(0);
#pragma unroll
            for (int kk = 8; kk < 16; ++kk) {
                union { u32x4 u; bf8 v; } A; A.u = au[kk];
                int e = (col * 512 + kk * 32 + kgrp * 8) ^ ((col & 7) << 3);
                accR = mfma16(A.v, *reinterpret_cast<const bf8*>(&sW[0][e]), accR);
                accR = mfma16(A.v, *reinterpret_cast<const bf8*>(&sW[1][e]), accR);
                accM = mfma16(A.v, *reinterpret_cast<const bf8*>(&sW[2][e]), accM);
                accM = mfma16(A.v, *reinterpret_cast<const bf8*>(&sW[3][e]), accM);
                accT = mfma16(A.v, *reinterpret_cast<const bf8*>(&sW[8][e]), accT);
            }
            wait_lds_ge(&sBdone, ph - 2);
#pragma unroll
            for (int r = 0; r < 4; ++r)
                sTi1[ph & 1][(kgrp * 4 + r) * 16 + col] = accT[r] + sB[4][col];
            if (lane == 0) set_lds(&sAready, ph);

            if (ph < T_STEPS) {
                float mn[4];
#pragma unroll
                for (int r = 0; r < 4; ++r) {
                    float retain = sigf(accR[r] + sB[0][col]);
                    float merge  = sigf(accM[r] + sB[1][col]);
                    float cv = tanhfast(cs[r] + retain * t0v[r]);
                    cs[r] = cv;
                    mn[r] = (1.f - merge) * t0v[r] + merge * cv;
                }
#pragma unroll
                for (int r = 0; r < 4; ++r) {
                    float hi = __shfl_xor(mn[r], 1, 64);
                    if (!(col & 1)) {
                        int row = rbrow + kgrp * 4 + r;
                        __hip_atomic_store(&ring0d[(ph & 1) * 8192 + rank * 256 + row * 8 + (col >> 1)],
                                           pack2(mn[r], hi), __ATOMIC_RELAXED,
                                           __HIP_MEMORY_SCOPE_AGENT);
                    }
                }
                asm volatile("s_waitcnt vmcnt(0)" ::: "memory");
                if (lane == 0)
                    __hip_atomic_store(&flagsA[rank * 16], (unsigned)(ph + 1), __ATOMIC_RELAXED,
                                       __HIP_MEMORY_SCOPE_AGENT);
                // hand mn to C (C does all out-stores)
                wait_lds_ge(&sCdone, ph - 2);
#pragma unroll
                for (int r = 0; r < 4; ++r)
                    sMn0[ph & 1][(kgrp * 4 + r) * 16 + col] = mn[r];
                if (lane == 0) set_lds(&sAout, ph);
            }
        }
#pragma unroll
        for (int r = 0; r < 4; ++r) {
            int b = rbrow + kgrp * 4 + r;
            fc[((size_t)b * 2 + 0) * 512 + h0 + col] = cs[r];
        }
    } else if (wid == 1) {
        // ============ wave B: layer-1 (1-phase slack) ============
#pragma unroll 1
        for (int ph = 1; ph <= T_STEPS; ++ph) {
            if (ph >= 2) poll_flags(flagsB, (unsigned)(ph - 1), lane);
            u32x4 au[16];
            {
                const unsigned* rp = ring1d + (ph & 1) * 8192
                                   + (rbrow + col) * 8 + (kgrp & 1) * 4;
#pragma unroll
                for (int kk = 0; kk < 16; ++kk)
                    asm volatile("global_load_dwordx4 %0, %1, off sc1"
                                 : "=v"(au[kk]) : "v"(rp + (2 * kk + (kgrp >> 1)) * 256));
                asm volatile("s_waitcnt vmcnt(0)" ::: "memory");
                __builtin_amdgcn_sched_barrier(0);
            }
            f4 accR = {0.f, 0.f, 0.f, 0.f};
            f4 accM = {0.f, 0.f, 0.f, 0.f};
#pragma unroll
            for (int kk = 0; kk < 16; ++kk) {
                union { u32x4 u; bf8 v; } A; A.u = au[kk];
                int e = (col * 512 + kk * 32 + kgrp * 8) ^ ((col & 7) << 3);
                accR = mfma16(A.v, *reinterpret_cast<const bf8*>(&sW[4][e]), accR);
                accR = mfma16(A.v, *reinterpret_cast<const bf8*>(&sW[5][e]), accR);
                accM = mfma16(A.v, *reinterpret_cast<const bf8*>(&sW[6][e]), accM);
                accM = mfma16(A.v, *reinterpret_cast<const bf8*>(&sW[7][e]), accM);
            }
            wait_lds_ge(&sAready, ph);
            float t1v[4];
#pragma unroll
            for (int r = 0; r < 4; ++r)
                t1v[r] = sTi1[ph & 1][(kgrp * 4 + r) * 16 + col];
            if (lane == 0) set_lds(&sBdone, ph);
            float mn[4];
#pragma unroll
            for (int r = 0; r < 4; ++r) {
                float retain = sigf(accR[r] + sB[2][col]);
                float merge  = sigf(accM[r] + sB[3][col]);
                float cv = tanhfast(cs[r] + retain * t1v[r]);
                cs[r] = cv;
                mn[r] = (1.f - merge) * t1v[r] + merge * cv;
            }
#pragma unroll
            for (int r = 0; r < 4; ++r) {
                float hi = __shfl_xor(mn[r], 1, 64);
                if (!(col & 1)) {
                    int row = rbrow + kgrp * 4 + r;
                    __hip_atomic_store(&ring1d[((ph + 1) & 1) * 8192 + rank * 256 + row * 8 + (col >> 1)],
                                       pack2(mn[r], hi), __ATOMIC_RELAXED,
                                       __HIP_MEMORY_SCOPE_AGENT);
                }
            }
            asm volatile("s_waitcnt vmcnt(0)" ::: "memory");
            if (lane == 0)
                __hip_atomic_store(&flagsB[rank * 16], (unsigned)ph, __ATOMIC_RELAXED,
                                   __HIP_MEMORY_SCOPE_AGENT);
            // hand mn to C
            wait_lds_ge(&sCdone, ph - 2);
#pragma unroll
            for (int r = 0; r < 4; ++r)
                sMn1[ph & 1][(kgrp * 4 + r) * 16 + col] = mn[r];
            if (lane == 0) set_lds(&sB1rdy, ph);
        }
#pragma unroll
        for (int r = 0; r < 4; ++r) {
            int b = rbrow + kgrp * 4 + r;
            fc[((size_t)b * 2 + 1) * 512 + h0 + col] = cs[r];
        }
    } else {
        // ============ wave C: all output stores ============
#pragma unroll 1
        for (int ph = 0; ph <= T_STEPS; ++ph) {
            float m0[4], m1[4];
            bool has0 = (ph < T_STEPS), has1 = (ph >= 1);
            if (has0) {
                wait_lds_ge(&sAout, ph);
#pragma unroll
                for (int r = 0; r < 4; ++r)
                    m0[r] = sMn0[ph & 1][(kgrp * 4 + r) * 16 + col];
            }
            if (has1) {
                wait_lds_ge(&sB1rdy, ph);
#pragma unroll
                for (int r = 0; r < 4; ++r)
                    m1[r] = sMn1[ph & 1][(kgrp * 4 + r) * 16 + col];
            }
            if (lane == 0) set_lds(&sCdone, ph);
            if (has0) {
#pragma unroll
                for (int r = 0; r < 4; ++r) {
                    int b = rbrow + kgrp * 4 + r;
                    size_t ob = ((size_t)b * 1024 + ph) * 1024 + h0 + col;
                    __builtin_nontemporal_store(m0[r], out + ob);
                    __builtin_nontemporal_store(m0[r], out + (size_t)33554432 + ob);
                }
            }
            if (has1) {
#pragma unroll
                for (int r = 0; r < 4; ++r) {
                    int b = rbrow + kgrp * 4 + r;
                    size_t ob = ((size_t)b * 1024 + (ph - 1)) * 1024 + 512 + h0 + col;
                    __builtin_nontemporal_store(m1[r], out + ob);
                    __builtin_nontemporal_store(m1[r], out + (size_t)33554432 + ob);
                }
            }
        }
    }
}

__global__ __launch_bounds__(256) void k_final(const float* __restrict__ fc,
                                               float* __restrict__ seg2)
{
    size_t id = (size_t)blockIdx.x * 256 + threadIdx.x;
    size_t gs = (size_t)gridDim.x * 256;
    for (size_t i = id; i < (size_t)8388608; i += gs) {
        size_t flat = i * 4;
        int h = (int)(flat & 511);
        int l = (int)((flat >> 9) & 1);
        int b = (int)(flat >> 20);
        f4 v = *reinterpret_cast<const f4*>(&fc[((size_t)b * 2 + l) * 512 + h]);
        *reinterpret_cast<f4*>(&seg2[flat]) = v;
    }
}

extern "C" void kernel_launch(void* const* d_in, const int* in_sizes, int n_in,
                              void* d_out, int out_size, void* d_ws, size_t ws_size,
                              hipStream_t stream)
{
    const float* x     = (const float*)d_in[0];
    const float* w_in0 = (const float*)d_in[1];
    const float* b_in0 = (const float*)d_in[2];
    const float* wh0   = (const float*)d_in[3];
    const float* bh0   = (const float*)d_in[4];
    const float* win1  = (const float*)d_in[5];
    const float* bin1  = (const float*)d_in[6];
    const float* wh1   = (const float*)d_in[7];
    const float* bh1   = (const float*)d_in[8];
    float* out = (float*)d_out;

    float*  seg2 = out + (size_t)2 * 33554432;
    float*  ti0  = seg2;
    __bf16* xbf  = (__bf16*)(ti0 + 16777216);
    __bf16* w0hi = xbf + 16777216;
    __bf16* w0lo = w0hi + 262144;

    k_init<<<1024, 256, 0, stream>>>(x, w_in0, xbf, w0hi, w0lo, (unsigned*)d_ws);
    k_pregemm<<<2048, 256, 0, stream>>>(xbf, w0hi, w0lo, b_in0, ti0);
    k_recur<<<64, 192, 0, stream>>>(wh0, bh0, win1, bin1, wh1, bh1, ti0, out,
                                    (unsigned*)d_ws);
    k_final<<<1024, 256, 0, stream>>>((const float*)((unsigned*)d_ws + 34816), seg2);
}

// Round 9
// 4310.117 us; speedup vs baseline: 1.7567x; 1.0392x over previous
//
#include <hip/hip_runtime.h>

// B=32, T=1024, I=H=512, 2H=1024.
// 64 WGs x 192 thr (3 waves): A=layer0 (binding cycle), B=layer1 (1-phase
// slack), C=all output stores. r8 protocol (validated) plus: early flag
// probes (speculative observe), ti0 prefetch folded into store drain,
// intra-WG handoffs moved off the inter-WG critical path.

#define T_STEPS 1024

typedef __bf16 bf8 __attribute__((ext_vector_type(8)));
typedef float  f4  __attribute__((ext_vector_type(4)));
typedef unsigned u32x4 __attribute__((ext_vector_type(4)));

__device__ __forceinline__ f4 mfma16(bf8 a, bf8 b, f4 c) {
    return __builtin_amdgcn_mfma_f32_16x16x32_bf16(a, b, c, 0, 0, 0);
}
__device__ __forceinline__ float sigf(float x)     { return 1.f / (1.f + __expf(-x)); }
__device__ __forceinline__ float tanhfast(float x) { return 1.f - 2.f / (1.f + __expf(2.f * x)); }
__device__ __forceinline__ unsigned pack2(float lo, float hi) {
    union { __bf16 h; unsigned short u; } a, b;
    a.h = (__bf16)lo; b.h = (__bf16)hi;
    return ((unsigned)b.u << 16) | (unsigned)a.u;
}
__device__ __forceinline__ void wait_lds_ge(int* p, int tgt) {
    while (__hip_atomic_load(p, __ATOMIC_ACQUIRE, __HIP_MEMORY_SCOPE_WORKGROUP) < tgt)
        __builtin_amdgcn_s_sleep(1);
}
__device__ __forceinline__ void set_lds(int* p, int v) {
    __hip_atomic_store(p, v, __ATOMIC_RELEASE, __HIP_MEMORY_SCOPE_WORKGROUP);
}
// poll 32 scattered flags (64B stride): lanes<32 load, others vote true
__device__ __forceinline__ void poll_flags(const unsigned* fbase, unsigned tgt, int lane) {
    while (true) {
        unsigned v = 0xFFFFFFFFu;
        if (lane < 32)
            v = __hip_atomic_load(fbase + lane * 16, __ATOMIC_RELAXED,
                                  __HIP_MEMORY_SCOPE_AGENT);
        if (__ballot(v >= tgt) == ~0ull) break;
        __builtin_amdgcn_s_sleep(1);
    }
    __builtin_amdgcn_sched_barrier(0);
}

// ws layout (u32 units):
//   [0,1024)      : flagsA  (mhalf m at m*512 + rank*16)
//   [1024,2048)   : flagsB
//   [2048,18432)  : ring0  [slot2][rank32][row32][pair8] u32
//   [18432,34816) : ring1
//   [34816,67584) : final_c f32 [32][2][512]
// d_out (f32): seg0 out1, seg1 out2, seg2 con; seg2 scratch during run:
//   ti0 f32 [T*32][512] @ +0; xbf bf16 @ +16777216 f32; w0hi/w0lo next.

__global__ __launch_bounds__(256) void k_init(const float* __restrict__ x,
                                              const float* __restrict__ w_in0,
                                              __bf16* __restrict__ xbf,
                                              __bf16* __restrict__ w0hi,
                                              __bf16* __restrict__ w0lo,
                                              unsigned* __restrict__ ws)
{
    size_t id = (size_t)blockIdx.x * 256 + threadIdx.x;
    size_t gs = (size_t)gridDim.x * 256;
    for (size_t i = id; i < 34816; i += gs) ws[i] = 0u;   // flags + rings
    for (size_t i = id; i < (size_t)16777216; i += gs) {
        size_t r = i >> 9, c = i & 511;
        size_t b = r & 31, t = r >> 5;
        xbf[i] = (__bf16)x[(((b << 10) + t) << 9) + c];
    }
    for (size_t i = id; i < (size_t)262144; i += gs) {
        size_t n = i >> 9, k = i & 511;
        float v = w_in0[(k << 9) + n];
        __bf16 h = (__bf16)v;
        w0hi[i] = h;
        w0lo[i] = (__bf16)(v - (float)h);
    }
}

__global__ __launch_bounds__(256) void k_pregemm(const __bf16* __restrict__ xbf,
                                                 const __bf16* __restrict__ w0hi,
                                                 const __bf16* __restrict__ w0lo,
                                                 const float* __restrict__ b_in0,
                                                 float* __restrict__ ti0)
{
    int tid = threadIdx.x, lane = tid & 63, wid = tid >> 6;
    int wg = blockIdx.x;
    int mbase = (wg & 511) * 64 + wid * 16;
    int nbase = (wg >> 9) * 128;
    int col = lane & 15, kgrp = lane >> 4;
    f4 acc[8];
#pragma unroll
    for (int i = 0; i < 8; ++i) acc[i] = (f4){0.f, 0.f, 0.f, 0.f};
    const __bf16* ap = xbf + (size_t)(mbase + col) * 512 + kgrp * 8;
    for (int kk = 0; kk < 16; ++kk) {
        bf8 a = *reinterpret_cast<const bf8*>(ap + kk * 32);
        const __bf16* wb = w0hi + (size_t)(nbase + col) * 512 + kk * 32 + kgrp * 8;
        const __bf16* wl = w0lo + (size_t)(nbase + col) * 512 + kk * 32 + kgrp * 8;
#pragma unroll
        for (int ct = 0; ct < 8; ++ct) {
            bf8 bh = *reinterpret_cast<const bf8*>(wb + (size_t)ct * 16 * 512);
            bf8 bl = *reinterpret_cast<const bf8*>(wl + (size_t)ct * 16 * 512);
            acc[ct] = mfma16(a, bh, acc[ct]);
            acc[ct] = mfma16(a, bl, acc[ct]);
        }
    }
#pragma unroll
    for (int ct = 0; ct < 8; ++ct) {
        int c = nbase + ct * 16 + col;
        float bias = b_in0[c];
#pragma unroll
        for (int r = 0; r < 4; ++r) {
            int row = mbase + kgrp * 4 + r;
            ti0[(size_t)row * 512 + c] = acc[ct][r] + bias;
        }
    }
}

// ---------------- persistent recurrence
__global__ __launch_bounds__(192, 1) void k_recur(
    const float* __restrict__ wh0, const float* __restrict__ bh0g,
    const float* __restrict__ win1, const float* __restrict__ bin1g,
    const float* __restrict__ wh1, const float* __restrict__ bh1g,
    const float* __restrict__ ti0,
    float* __restrict__ out,
    unsigned* __restrict__ ws)
{
    // planes: 0:w0r_hi 1:w0r_lo 2:w0m_hi 3:w0m_lo 4:w1r_hi 5:w1r_lo 6:w1m_hi 7:w1m_lo 8:wt_hi
    __shared__ __bf16 sW[9][8192];
    __shared__ float  sTi1[2][256];
    __shared__ float  sMn0[2][256];
    __shared__ float  sMn1[2][256];
    __shared__ float  sB[5][16];
    __shared__ int    sAready, sAout, sB1rdy, sBdone, sCdone;

    int tid = threadIdx.x, lane = tid & 63, wid = tid >> 6;   // 0=A,1=B,2=C
    int wg = blockIdx.x;
    int rank  = wg & 31;
    int mhalf = wg >> 5;

    unsigned* flagsA = ws + mhalf * 512;
    unsigned* flagsB = ws + 1024 + mhalf * 512;
    unsigned* ring0d = ws + 2048;
    unsigned* ring1d = ws + 18432;
    float* fc = (float*)(ws + 34816);

    int h0 = rank * 16;
    int col = lane & 15, kgrp = lane >> 4;
    int rbrow = mhalf * 16;

    for (int i = tid; i < 8192; i += 192) {
        int cl = i & 15, k = i >> 4;
        int sw = (cl * 512 + k) ^ ((cl & 7) << 3);
        float v0r = wh0[(size_t)k * 1024 + h0 + cl];
        float v0m = wh0[(size_t)k * 1024 + 512 + h0 + cl];
        float v1r = wh1[(size_t)k * 1024 + h0 + cl];
        float v1m = wh1[(size_t)k * 1024 + 512 + h0 + cl];
        float vt  = win1[(size_t)k * 512 + h0 + cl];
        __bf16 a;
        a = (__bf16)v0r; sW[0][sw] = a; sW[1][sw] = (__bf16)(v0r - (float)a);
        a = (__bf16)v0m; sW[2][sw] = a; sW[3][sw] = (__bf16)(v0m - (float)a);
        a = (__bf16)v1r; sW[4][sw] = a; sW[5][sw] = (__bf16)(v1r - (float)a);
        a = (__bf16)v1m; sW[6][sw] = a; sW[7][sw] = (__bf16)(v1m - (float)a);
        sW[8][sw] = (__bf16)vt;
    }
    if (tid < 16) {
        sB[0][tid] = bh0g[h0 + tid];
        sB[1][tid] = bh0g[512 + h0 + tid];
        sB[2][tid] = bh1g[h0 + tid];
        sB[3][tid] = bh1g[512 + h0 + tid];
        sB[4][tid] = bin1g[h0 + tid];
    }
    if (tid == 0) { sAready = -1; sAout = -1; sB1rdy = -1; sBdone = -1; sCdone = -1; }
    __syncthreads();

    float cs[4] = {0.f, 0.f, 0.f, 0.f};

    if (wid == 0) {
        // ============ wave A: layer-0 cycle + ti1 for B ============
        float t0n[4];
#pragma unroll
        for (int r = 0; r < 4; ++r)
            asm volatile("global_load_dword %0, %1, off"
                         : "=v"(t0n[r])
                         : "v"(ti0 + ((size_t)(rbrow + kgrp * 4 + r)) * 512 + h0 + col));
        unsigned pv = 0;
#pragma unroll 1
        for (int ph = 0; ph <= T_STEPS; ++ph) {
            if (ph > 0) {
                // early-probe check: probes (and ti0 prefetch) already in flight
                asm volatile("s_waitcnt vmcnt(0)" ::: "memory");
                __builtin_amdgcn_sched_barrier(0);
                unsigned v = (lane < 32 && lane != rank) ? pv : 0xFFFFFFFFu;
                if (__ballot(v >= (unsigned)ph) != ~0ull)
                    poll_flags(flagsA, (unsigned)ph, lane);
                __builtin_amdgcn_sched_barrier(0);
            }
            // rank-major ring pull: afr[kk] from rank (2kk + kgrp/2)
            u32x4 au[16];
            {
                const unsigned* rp = ring0d + ((ph + 1) & 1) * 8192
                                   + (rbrow + col) * 8 + (kgrp & 1) * 4;
#pragma unroll
                for (int kk = 0; kk < 16; ++kk)
                    asm volatile("global_load_dwordx4 %0, %1, off sc1"
                                 : "=v"(au[kk]) : "v"(rp + (2 * kk + (kgrp >> 1)) * 256));
            }
            f4 accR = {0.f, 0.f, 0.f, 0.f};
            f4 accM = {0.f, 0.f, 0.f, 0.f};
            f4 accT = {0.f, 0.f, 0.f, 0.f};
            asm volatile("s_waitcnt vmcnt(8)" ::: "memory");
            __builtin_amdgcn_sched_barrier(0);
#pragma unroll
            for (int kk = 0; kk < 8; ++kk) {
                union { u32x4 u; bf8 v; } A; A.u = au[kk];
                int e = (col * 512 + kk * 32 + kgrp * 8) ^ ((col & 7) << 3);
                accR = mfma16(A.v, *reinterpret_cast<const bf8*>(&sW[0][e]), accR);
                accR = mfma16(A.v, *reinterpret_cast<const bf8*>(&sW[1][e]), accR);
                accM = mfma16(A.v, *reinterpret_cast<const bf8*>(&sW[2][e]), accM);
                accM = mfma16(A.v, *reinterpret_cast<const bf8*>(&sW[3][e]), accM);
                accT = mfma16(A.v, *reinterpret_cast<const bf8*>(&sW[8][e]), accT);
            }
            asm volatile("s_waitcnt vmcnt(0)" ::: "memory");
            __builtin_amdgcn_sched_barrier(0);
#pragma unroll
            for (int kk = 8; kk < 16; ++kk) {
                union { u32x4 u; bf8 v; } A; A.u = au[kk];
                int e = (col * 512 + kk * 32 + kgrp * 8) ^ ((col & 7) << 3);
                accR = mfma16(A.v, *reinterpret_cast<const bf8*>(&sW[0][e]), accR);
                accR = mfma16(A.v, *reinterpret_cast<const bf8*>(&sW[1][e]), accR);
                accM = mfma16(A.v, *reinterpret_cast<const bf8*>(&sW[2][e]), accM);
                accM = mfma16(A.v, *reinterpret_cast<const bf8*>(&sW[3][e]), accM);
                accT = mfma16(A.v, *reinterpret_cast<const bf8*>(&sW[8][e]), accT);
            }

            float mn[4];
            if (ph < T_STEPS) {
                // cell math (consumes prefetched t0n), ring stores, drain, flag
#pragma unroll
                for (int r = 0; r < 4; ++r) {
                    float retain = sigf(accR[r] + sB[0][col]);
                    float merge  = sigf(accM[r] + sB[1][col]);
                    float cv = tanhfast(cs[r] + retain * t0n[r]);
                    cs[r] = cv;
                    mn[r] = (1.f - merge) * t0n[r] + merge * cv;
                }
#pragma unroll
                for (int r = 0; r < 4; ++r) {
                    float hi = __shfl_xor(mn[r], 1, 64);
                    if (!(col & 1)) {
                        int row = rbrow + kgrp * 4 + r;
                        __hip_atomic_store(&ring0d[(ph & 1) * 8192 + rank * 256 + row * 8 + (col >> 1)],
                                           pack2(mn[r], hi), __ATOMIC_RELAXED,
                                           __HIP_MEMORY_SCOPE_AGENT);
                    }
                }
                if (ph + 1 < T_STEPS) {
                    // ti0 prefetch folded into the store drain
#pragma unroll
                    for (int r = 0; r < 4; ++r)
                        asm volatile("global_load_dword %0, %1, off"
                                     : "=v"(t0n[r])
                                     : "v"(ti0 + ((size_t)(ph + 1) * 32 + rbrow + kgrp * 4 + r) * 512 + h0 + col));
                }
                asm volatile("s_waitcnt vmcnt(0)" ::: "memory");
                if (lane == 0)
                    __hip_atomic_store(&flagsA[rank * 16], (unsigned)(ph + 1), __ATOMIC_RELAXED,
                                       __HIP_MEMORY_SCOPE_AGENT);
                // early probe for next phase's check
                if (lane < 32 && lane != rank)
                    asm volatile("global_load_dword %0, %1, off sc1"
                                 : "=v"(pv) : "v"(flagsA + lane * 16));
            }

            // intra-WG handoffs AFTER the inter-WG critical path
            wait_lds_ge(&sBdone, ph - 2);
#pragma unroll
            for (int r = 0; r < 4; ++r)
                sTi1[ph & 1][(kgrp * 4 + r) * 16 + col] = accT[r] + sB[4][col];
            if (lane == 0) set_lds(&sAready, ph);

            if (ph < T_STEPS) {
                wait_lds_ge(&sCdone, ph - 2);
#pragma unroll
                for (int r = 0; r < 4; ++r)
                    sMn0[ph & 1][(kgrp * 4 + r) * 16 + col] = mn[r];
                if (lane == 0) set_lds(&sAout, ph);
            }
        }
#pragma unroll
        for (int r = 0; r < 4; ++r) {
            int b = rbrow + kgrp * 4 + r;
            fc[((size_t)b * 2 + 0) * 512 + h0 + col] = cs[r];
        }
    } else if (wid == 1) {
        // ============ wave B: layer-1 (1-phase slack) ============
#pragma unroll 1
        for (int ph = 1; ph <= T_STEPS; ++ph) {
            if (ph >= 2) poll_flags(flagsB, (unsigned)(ph - 1), lane);
            u32x4 au[16];
            {
                const unsigned* rp = ring1d + (ph & 1) * 8192
                                   + (rbrow + col) * 8 + (kgrp & 1) * 4;
#pragma unroll
                for (int kk = 0; kk < 16; ++kk)
                    asm volatile("global_load_dwordx4 %0, %1, off sc1"
                                 : "=v"(au[kk]) : "v"(rp + (2 * kk + (kgrp >> 1)) * 256));
                asm volatile("s_waitcnt vmcnt(0)" ::: "memory");
                __builtin_amdgcn_sched_barrier(0);
            }
            f4 accR = {0.f, 0.f, 0.f, 0.f};
            f4 accM = {0.f, 0.f, 0.f, 0.f};
#pragma unroll
            for (int kk = 0; kk < 16; ++kk) {
                union { u32x4 u; bf8 v; } A; A.u = au[kk];
                int e = (col * 512 + kk * 32 + kgrp * 8) ^ ((col & 7) << 3);
                accR = mfma16(A.v, *reinterpret_cast<const bf8*>(&sW[4][e]), accR);
                accR = mfma16(A.v, *reinterpret_cast<const bf8*>(&sW[5][e]), accR);
                accM = mfma16(A.v, *reinterpret_cast<const bf8*>(&sW[6][e]), accM);
                accM = mfma16(A.v, *reinterpret_cast<const bf8*>(&sW[7][e]), accM);
            }
            wait_lds_ge(&sAready, ph);
            float t1v[4];
#pragma unroll
            for (int r = 0; r < 4; ++r)
                t1v[r] = sTi1[ph & 1][(kgrp * 4 + r) * 16 + col];
            if (lane == 0) set_lds(&sBdone, ph);
            float mn[4];
#pragma unroll
            for (int r = 0; r < 4; ++r) {
                float retain = sigf(accR[r] + sB[2][col]);
                float merge  = sigf(accM[r] + sB[3][col]);
                float cv = tanhfast(cs[r] + retain * t1v[r]);
                cs[r] = cv;
                mn[r] = (1.f - merge) * t1v[r] + merge * cv;
            }
#pragma unroll
            for (int r = 0; r < 4; ++r) {
                float hi = __shfl_xor(mn[r], 1, 64);
                if (!(col & 1)) {
                    int row = rbrow + kgrp * 4 + r;
                    __hip_atomic_store(&ring1d[((ph + 1) & 1) * 8192 + rank * 256 + row * 8 + (col >> 1)],
                                       pack2(mn[r], hi), __ATOMIC_RELAXED,
                                       __HIP_MEMORY_SCOPE_AGENT);
                }
            }
            asm volatile("s_waitcnt vmcnt(0)" ::: "memory");
            if (lane == 0)
                __hip_atomic_store(&flagsB[rank * 16], (unsigned)ph, __ATOMIC_RELAXED,
                                   __HIP_MEMORY_SCOPE_AGENT);
            // hand mn to C
            wait_lds_ge(&sCdone, ph - 2);
#pragma unroll
            for (int r = 0; r < 4; ++r)
                sMn1[ph & 1][(kgrp * 4 + r) * 16 + col] = mn[r];
            if (lane == 0) set_lds(&sB1rdy, ph);
        }
#pragma unroll
        for (int r = 0; r < 4; ++r) {
            int b = rbrow + kgrp * 4 + r;
            fc[((size_t)b * 2 + 1) * 512 + h0 + col] = cs[r];
        }
    } else {
        // ============ wave C: all output stores ============
#pragma unroll 1
        for (int ph = 0; ph <= T_STEPS; ++ph) {
            float m0[4], m1[4];
            bool has0 = (ph < T_STEPS), has1 = (ph >= 1);
            if (has0) {
                wait_lds_ge(&sAout, ph);
#pragma unroll
                for (int r = 0; r < 4; ++r)
                    m0[r] = sMn0[ph & 1][(kgrp * 4 + r) * 16 + col];
            }
            if (has1) {
                wait_lds_ge(&sB1rdy, ph);
#pragma unroll
                for (int r = 0; r < 4; ++r)
                    m1[r] = sMn1[ph & 1][(kgrp * 4 + r) * 16 + col];
            }
            if (lane == 0) set_lds(&sCdone, ph);
            if (has0) {
#pragma unroll
                for (int r = 0; r < 4; ++r) {
                    int b = rbrow + kgrp * 4 + r;
                    size_t ob = ((size_t)b * 1024 + ph) * 1024 + h0 + col;
                    __builtin_nontemporal_store(m0[r], out + ob);
                    __builtin_nontemporal_store(m0[r], out + (size_t)33554432 + ob);
                }
            }
            if (has1) {
#pragma unroll
                for (int r = 0; r < 4; ++r) {
                    int b = rbrow + kgrp * 4 + r;
                    size_t ob = ((size_t)b * 1024 + (ph - 1)) * 1024 + 512 + h0 + col;
                    __builtin_nontemporal_store(m1[r], out + ob);
                    __builtin_nontemporal_store(m1[r], out + (size_t)33554432 + ob);
                }
            }
        }
    }
}

__global__ __launch_bounds__(256) void k_final(const float* __restrict__ fc,
                                               float* __restrict__ seg2)
{
    size_t id = (size_t)blockIdx.x * 256 + threadIdx.x;
    size_t gs = (size_t)gridDim.x * 256;
    for (size_t i = id; i < (size_t)8388608; i += gs) {
        size_t flat = i * 4;
        int h = (int)(flat & 511);
        int l = (int)((flat >> 9) & 1);
        int b = (int)(flat >> 20);
        f4 v = *reinterpret_cast<const f4*>(&fc[((size_t)b * 2 + l) * 512 + h]);
        *reinterpret_cast<f4*>(&seg2[flat]) = v;
    }
}

extern "C" void kernel_launch(void* const* d_in, const int* in_sizes, int n_in,
                              void* d_out, int out_size, void* d_ws, size_t ws_size,
                              hipStream_t stream)
{
    const float* x     = (const float*)d_in[0];
    const float* w_in0 = (const float*)d_in[1];
    const float* b_in0 = (const float*)d_in[2];
    const float* wh0   = (const float*)d_in[3];
    const float* bh0   = (const float*)d_in[4];
    const float* win1  = (const float*)d_in[5];
    const float* bin1  = (const float*)d_in[6];
    const float* wh1   = (const float*)d_in[7];
    const float* bh1   = (const float*)d_in[8];
    float* out = (float*)d_out;

    float*  seg2 = out + (size_t)2 * 33554432;
    float*  ti0  = seg2;
    __bf16* xbf  = (__bf16*)(ti0 + 16777216);
    __bf16* w0hi = xbf + 16777216;
    __bf16* w0lo = w0hi + 262144;

    k_init<<<1024, 256, 0, stream>>>(x, w_in0, xbf, w0hi, w0lo, (unsigned*)d_ws);
    k_pregemm<<<2048, 256, 0, stream>>>(xbf, w0hi, w0lo, b_in0, ti0);
    k_recur<<<64, 192, 0, stream>>>(wh0, bh0, win1, bin1, wh1, bh1, ti0, out,
                                    (unsigned*)d_ws);
    k_final<<<1024, 256, 0, stream>>>((const float*)((unsigned*)d_ws + 34816), seg2);
}